// Round 11
// baseline (2153.970 us; speedup 1.0000x reference)
//
#include <hip/hip_runtime.h>
#include <stdint.h>

#define NN 100000
#define RR 4
#define EE 1600000
#define DD 128
#define TN 32
#define BLK 256
#define NB 98     // ceil((NN+1)/1024) scan blocks; ALSO # of 1024-node buckets
#define CHUNK 2048

typedef unsigned int u32;
typedef unsigned short u16;

__device__ __forceinline__ u16 f2bf(float f) {
  union { float f; u32 i; } c; c.f = f;
  const u32 lsb = (c.i >> 16) & 1u;
  c.i += 0x7fffu + lsb;  // round-to-nearest-even
  return (u16)(c.i >> 16);
}
__device__ __forceinline__ u32 pack2(float a, float b) {
  return (u32)f2bf(a) | ((u32)f2bf(b) << 16);
}
__device__ __forceinline__ float u2f(u32 u) {
  union { u32 i; float f; } c; c.i = u; return c.f;
}

// ---------- pass 1: histogram of dst (offsets shifted by +1) ----------
__global__ __launch_bounds__(256)
void k_hist(const int* __restrict__ dst, int* __restrict__ off) {
  const int r = blockIdx.y;
  const long e = (long)blockIdx.x * 256 + threadIdx.x;
  if (e >= EE) return;
  const int d = dst[(size_t)r * EE + e];
  atomicAdd(&off[(size_t)r * (NN + 1) + d + 1], 1);
}

// ---------- pass 2a: block-local inclusive scan ----------
__global__ __launch_bounds__(1024)
void k_scan1(int* __restrict__ off, int* __restrict__ bsum) {
  const int r = blockIdx.y;
  int* a = off + (size_t)r * (NN + 1);
  __shared__ int tmp[1024];
  const int t = threadIdx.x;
  const int idx = blockIdx.x * 1024 + t;
  tmp[t] = (idx <= NN) ? a[idx] : 0;
  __syncthreads();
  for (int o = 1; o < 1024; o <<= 1) {
    const int y = (t >= o) ? tmp[t - o] : 0;
    __syncthreads();
    tmp[t] += y;
    __syncthreads();
  }
  if (idx <= NN) a[idx] = tmp[t];
  if (t == 1023) bsum[r * NB + blockIdx.x] = tmp[1023];
}

// ---------- pass 2b: scan the 98 block sums -> exclusive prefix ----------
__global__ __launch_bounds__(128)
void k_scan2(int* __restrict__ bsum) {
  const int r = blockIdx.x;
  __shared__ int tmp[128];
  const int t = threadIdx.x;
  const int v = (t < NB) ? bsum[r * NB + t] : 0;
  tmp[t] = v;
  __syncthreads();
  for (int o = 1; o < 128; o <<= 1) {
    const int y = (t >= o) ? tmp[t - o] : 0;
    __syncthreads();
    tmp[t] += y;
    __syncthreads();
  }
  if (t < NB) bsum[r * NB + t] = tmp[t] - v;  // exclusive
}

// ---------- pass 2c: add block prefix; emit cursor copy ----------
__global__ __launch_bounds__(1024)
void k_scan3(int* __restrict__ off, const int* __restrict__ bsum,
             int* __restrict__ cursor) {
  const int r = blockIdx.y;
  const int idx = blockIdx.x * 1024 + threadIdx.x;
  const int add = bsum[r * NB + blockIdx.x];
  int* a = off + (size_t)r * (NN + 1);
  if (idx <= NN) {
    const int v = a[idx] + add;
    a[idx] = v;
    if (idx < NN) cursor[(size_t)r * NN + idx] = v;
  }
}

// ---------- init coarse-bucket cursors from CSR offsets ----------
__global__ __launch_bounds__(256)
void k_initg(const int* __restrict__ off, int* __restrict__ gcur) {
  const int i = blockIdx.x * 256 + threadIdx.x;
  if (i < RR * NB) {
    const int r = i / NB, b = i % NB;
    gcur[i] = off[(size_t)r * (NN + 1) + (b << 10)];
  }
}

// ---------- pass 3a: coarse binning with LDS-staged dense writes ----------
__global__ __launch_bounds__(256)
void k_bin(const int* __restrict__ src, const int* __restrict__ dst,
           int* __restrict__ gcur, int2* __restrict__ pairs) {
  const int r = blockIdx.y;
  const long base = (long)blockIdx.x * CHUNK;
  const int t = threadIdx.x;
  __shared__ int hist[NB], lofs[NB], gbase[NB], hcur[NB];
  __shared__ int2 stage[CHUNK];  // 16 KB
  for (int i = t; i < NB; i += 256) hist[i] = 0;
  __syncthreads();
  int d[8], s[8];
#pragma unroll
  for (int k = 0; k < 8; ++k) {
    const long e = base + k * 256 + t;
    if (e < EE) {
      d[k] = dst[(size_t)r * EE + e];
      s[k] = src[(size_t)r * EE + e];
      atomicAdd(&hist[d[k] >> 10], 1);
    } else d[k] = -1;
  }
  __syncthreads();
  if (t == 0) {
    int run = 0;
    for (int b = 0; b < NB; ++b) { lofs[b] = run; run += hist[b]; }
  }
  __syncthreads();
  if (t < NB) {
    hcur[t] = 0;
    gbase[t] = hist[t] ? atomicAdd(&gcur[r * NB + t], hist[t]) : 0;
  }
  __syncthreads();
#pragma unroll
  for (int k = 0; k < 8; ++k) {
    if (d[k] >= 0) {
      const int b = d[k] >> 10;
      const int slot = lofs[b] + atomicAdd(&hcur[b], 1);
      stage[slot] = make_int2(d[k], s[k]);
    }
  }
  __syncthreads();
  const int total = (int)((EE - base < CHUNK) ? (EE - base) : CHUNK);
  for (int i = t; i < total; i += 256) {
    const int2 p = stage[i];
    const int b = p.x >> 10;
    pairs[(size_t)r * EE + gbase[b] + (i - lofs[b])] = p;
  }
}

// ---------- pass 3b: exact placement within L2-resident bucket window ----------
__global__ __launch_bounds__(256)
void k_place(const int2* __restrict__ pairs, const int* __restrict__ off,
             int* __restrict__ cursor, int* __restrict__ sorted) {
  const int r = blockIdx.y;
  const int b = blockIdx.x;
  const int nlo = b << 10;
  const int nhi = (nlo + 1024 < NN) ? nlo + 1024 : NN;
  const int span0 = off[(size_t)r * (NN + 1) + nlo];
  const int span1 = off[(size_t)r * (NN + 1) + nhi];
  for (int i = span0 + threadIdx.x; i < span1; i += 256) {
    const int2 p = pairs[(size_t)r * EE + i];
    const int pos = atomicAdd(&cursor[(size_t)r * NN + p.x], 1);
    sorted[(size_t)r * EE + pos] = p.y;
  }
}

// ---------- convert one relation's features to packed bf16 rows ----------
// nf16[n*64 + lane] holds dims {2*lane, 2*lane+1} of node n as bf16x2.
// Runs AFTER k_place; nf16 aliases the dead `pairs` region.
__global__ __launch_bounds__(256)
void k_cvt(const float* __restrict__ nf, u32* __restrict__ nf16, int r) {
  const long t = (long)blockIdx.x * 256 + threadIdx.x;
  if (t >= (long)NN * 64) return;
  const int n = (int)(t >> 6);
  const int l = (int)(t & 63);
  const float2 v = *(const float2*)(nf + ((size_t)n * RR + r) * DD + l * 2);
  nf16[t] = pack2(v.x, v.y);
}

// ---- copy one 32-row K-chunk of a 128x128 f32 weight into LDS (16 KB) ----
__device__ __forceinline__ void loadWc(const float* __restrict__ Wsrc, int chunk,
                                       float* __restrict__ sW, int tid) {
  const float4* src = (const float4*)(Wsrc + (size_t)chunk * 32 * DD);
  float4* dstv = (float4*)sW;
#pragma unroll
  for (int k = 0; k < 4; ++k) dstv[tid + k * BLK] = src[tid + k * BLK];  // 1024 float4
}

// ---- 4x4-blocked K=32-chunk gemm: acc[i][j] += A[rg+i][kbase+k] * W[k][c4+j] ----
__device__ __forceinline__ void gemm4x4(const float (*__restrict__ in)[DD],
                                        const float* __restrict__ sW,
                                        int rg, int c4, int kbase, float acc[4][4]) {
  for (int k4 = 0; k4 < 32; k4 += 4) {
    const float4 a0 = *(const float4*)(&in[rg + 0][kbase + k4]);
    const float4 a1 = *(const float4*)(&in[rg + 1][kbase + k4]);
    const float4 a2 = *(const float4*)(&in[rg + 2][kbase + k4]);
    const float4 a3 = *(const float4*)(&in[rg + 3][kbase + k4]);
    const float4 w0 = *(const float4*)(&sW[(k4 + 0) * DD + c4]);
    const float4 w1 = *(const float4*)(&sW[(k4 + 1) * DD + c4]);
    const float4 w2 = *(const float4*)(&sW[(k4 + 2) * DD + c4]);
    const float4 w3 = *(const float4*)(&sW[(k4 + 3) * DD + c4]);
#define ROWF(i, ai)                                                                               \
    acc[i][0] = fmaf(ai.x, w0.x, fmaf(ai.y, w1.x, fmaf(ai.z, w2.x, fmaf(ai.w, w3.x, acc[i][0])))); \
    acc[i][1] = fmaf(ai.x, w0.y, fmaf(ai.y, w1.y, fmaf(ai.z, w2.y, fmaf(ai.w, w3.y, acc[i][1])))); \
    acc[i][2] = fmaf(ai.x, w0.z, fmaf(ai.y, w1.z, fmaf(ai.z, w2.z, fmaf(ai.w, w3.z, acc[i][2])))); \
    acc[i][3] = fmaf(ai.x, w0.w, fmaf(ai.y, w1.w, fmaf(ai.z, w2.w, fmaf(ai.w, w3.w, acc[i][3]))));
    ROWF(0, a0) ROWF(1, a1) ROWF(2, a2) ROWF(3, a3)
#undef ROWF
  }
}

// ---- full 128-K gemm via 4 LDS chunks ----
__device__ __forceinline__ void gemm128c(const float (*__restrict__ in)[DD],
                                         const float* __restrict__ Wsrc,
                                         float* __restrict__ sW,
                                         int tid, int rg, int c4, float acc[4][4]) {
#pragma unroll
  for (int i = 0; i < 4; ++i)
#pragma unroll
    for (int jj = 0; jj < 4; ++jj) acc[i][jj] = 0.f;
#pragma unroll
  for (int c = 0; c < 4; ++c) {
    loadWc(Wsrc, c, sW, tid);
    __syncthreads();
    gemm4x4(in, sW, rg, c4, c * 32, acc);
    __syncthreads();
  }
}

// ------- fused: bf16 gather(CSR) + residual + MLP + LN + attention scores -------
__global__ __launch_bounds__(BLK)
void k_mlp(const float* __restrict__ nf, const u32* __restrict__ nf16,
           const float* __restrict__ W1, const float* __restrict__ b1,
           const float* __restrict__ W2, const float* __restrict__ b2,
           const float* __restrict__ Ws1, const float* __restrict__ Ws2,
           const float* __restrict__ gamma, const float* __restrict__ beta,
           const int* __restrict__ off, const int* __restrict__ sortedSrc,
           float* __restrict__ S, float* __restrict__ out, int r) {
  __shared__ float sA[TN][DD];                 // 16 KB
  __shared__ __align__(16) float sW[32 * DD];  // 16 KB  (total 32 KB -> 5 blocks/CU)

  const int tid = threadIdx.x;
  const int n0 = blockIdx.x * TN;
  const int rg = (tid >> 5) * 4;   // 8 row groups of 4
  const int c4 = (tid & 31) * 4;   // 32 col groups of 4

  // ---- stage rst = feat(f32) + bf16-gather(CSR) -> sA; wave owns 8 rows ----
  {
    const int wv = tid >> 6;
    const int lane = tid & 63;
    const int* ss = sortedSrc + (size_t)r * EE;
#pragma unroll
    for (int q = 0; q < 8; ++q) {
      const int i = wv * 8 + q;
      const int n = n0 + i;
      float2 a2 = make_float2(0.f, 0.f);
      if (n < NN) {
        a2 = *(const float2*)(nf + ((size_t)n * RR + r) * DD + lane * 2);
        const int e1 = off[(size_t)r * (NN + 1) + n + 1];
        int e = off[(size_t)r * (NN + 1) + n];
        for (; e + 7 < e1; e += 8) {  // unroll-8: 8 bf16 rows in flight
          u32 v[8];
#pragma unroll
          for (int k = 0; k < 8; ++k)
            v[k] = nf16[((size_t)ss[e + k] << 6) + lane];
#pragma unroll
          for (int k = 0; k < 8; ++k) {
            a2.x += u2f(v[k] << 16);
            a2.y += u2f(v[k] & 0xffff0000u);
          }
        }
        for (; e < e1; ++e) {
          const u32 v = nf16[((size_t)ss[e] << 6) + lane];
          a2.x += u2f(v << 16);
          a2.y += u2f(v & 0xffff0000u);
        }
      }
      *(float2*)(&sA[i][lane * 2]) = a2;
    }
  }
  __syncthreads();

  float acc[4][4];

  // ---- GEMM1 + bias + relu ----
  gemm128c(sA, W1, sW, tid, rg, c4, acc);
  {
    const float4 bb = *(const float4*)(&b1[c4]);
#pragma unroll
    for (int i = 0; i < 4; ++i)
      *(float4*)(&sA[rg + i][c4]) = make_float4(
          fmaxf(acc[i][0] + bb.x, 0.f), fmaxf(acc[i][1] + bb.y, 0.f),
          fmaxf(acc[i][2] + bb.z, 0.f), fmaxf(acc[i][3] + bb.w, 0.f));
  }
  __syncthreads();

  // ---- GEMM2 + bias + relu ----
  gemm128c(sA, W2, sW, tid, rg, c4, acc);
  {
    const float4 bb = *(const float4*)(&b2[c4]);
#pragma unroll
    for (int i = 0; i < 4; ++i)
      *(float4*)(&sA[rg + i][c4]) = make_float4(
          fmaxf(acc[i][0] + bb.x, 0.f), fmaxf(acc[i][1] + bb.y, 0.f),
          fmaxf(acc[i][2] + bb.z, 0.f), fmaxf(acc[i][3] + bb.w, 0.f));
  }
  __syncthreads();

  // ---- LayerNorm (8 threads/row, stats in registers via shfl) ----
  {
    const int i = tid >> 3;          // 0..31
    const int c0 = (tid & 7) * 16;
    float s = 0.f, s2 = 0.f;
    float hv[16];
#pragma unroll
    for (int c = 0; c < 16; ++c) {
      const float v = sA[i][c0 + c];
      hv[c] = v;
      s += v; s2 += v * v;
    }
#pragma unroll
    for (int off2 = 1; off2 < 8; off2 <<= 1) {
      s  += __shfl_xor(s, off2);
      s2 += __shfl_xor(s2, off2);
    }
    const float mu = s * (1.f / 128.f);
    const float var = fmaxf(s2 * (1.f / 128.f) - mu * mu, 0.f);
    const float rs = rsqrtf(var + 1e-5f);
    const int n = n0 + i;
#pragma unroll
    for (int c = 0; c < 16; ++c) {
      hv[c] = (hv[c] - mu) * rs * gamma[c0 + c] + beta[c0 + c];
      sA[i][c0 + c] = hv[c];   // own slice only: no cross-thread hazard
    }
    if (n < NN) {
      float4* op = (float4*)(out + ((size_t)n * RR + r) * DD + c0);
#pragma unroll
      for (int q = 0; q < 4; ++q)
        op[q] = make_float4(hv[q * 4], hv[q * 4 + 1], hv[q * 4 + 2], hv[q * 4 + 3]);
    }
  }
  __syncthreads();

  // ---- GEMM3: tanh(h @ Ws1[r]) ----
  gemm128c(sA, Ws1 + (size_t)r * DD * DD, sW, tid, rg, c4, acc);
#pragma unroll
  for (int i = 0; i < 4; ++i)
    *(float4*)(&sA[rg + i][c4]) = make_float4(
        tanhf(acc[i][0]), tanhf(acc[i][1]), tanhf(acc[i][2]), tanhf(acc[i][3]));
  {
    sW[tid]       = Ws2[(size_t)r * 512 + tid];
    sW[tid + 256] = Ws2[(size_t)r * 512 + tid + 256];
  }
  __syncthreads();

  // ---- scores = tanh(...) @ Ws2[r] -> S ----
  if (tid < TN * 4) {
    const int i = tid >> 2;
    const int k = tid & 3;
    float a = 0.f;
#pragma unroll 8
    for (int q = 0; q < DD; ++q) a = fmaf(sA[i][q], sW[q * 4 + k], a);
    const int n = n0 + i;
    if (n < NN) S[((size_t)r * NN + n) * 4 + k] = a;
  }
}

// -------- softmax over relations + final mix (in place on out) --------
__global__ __launch_bounds__(256)
void k_combine(const float* __restrict__ S, float* __restrict__ out) {
  const long gw = (((long)blockIdx.x * 256) + threadIdx.x) >> 6;
  const int lane = threadIdx.x & 63;
  if (gw >= NN) return;
  const int n = (int)gw;
  float a[4][4];
#pragma unroll
  for (int r = 0; r < 4; ++r)
#pragma unroll
    for (int k = 0; k < 4; ++k)
      a[r][k] = S[((size_t)r * NN + n) * 4 + k];
#pragma unroll
  for (int k = 0; k < 4; ++k) {
    const float m = fmaxf(fmaxf(a[0][k], a[1][k]), fmaxf(a[2][k], a[3][k]));
    const float e0 = expf(a[0][k] - m);
    const float e1 = expf(a[1][k] - m);
    const float e2 = expf(a[2][k] - m);
    const float e3 = expf(a[3][k] - m);
    const float inv = 1.f / (e0 + e1 + e2 + e3);
    a[0][k] = e0 * inv; a[1][k] = e1 * inv; a[2][k] = e2 * inv; a[3][k] = e3 * inv;
  }
  float2 hv[4];
#pragma unroll
  for (int k = 0; k < 4; ++k)
    hv[k] = *(const float2*)(out + ((size_t)n * RR + k) * DD + lane * 2);
#pragma unroll
  for (int r = 0; r < 4; ++r) {
    float2 o;
    o.x = a[r][0] * hv[0].x + a[r][1] * hv[1].x + a[r][2] * hv[2].x + a[r][3] * hv[3].x;
    o.y = a[r][0] * hv[0].y + a[r][1] * hv[1].y + a[r][2] * hv[2].y + a[r][3] * hv[3].y;
    *(float2*)(out + ((size_t)n * RR + r) * DD + lane * 2) = o;
  }
}

extern "C" void kernel_launch(void* const* d_in, const int* in_sizes, int n_in,
                              void* d_out, int out_size, void* d_ws, size_t ws_size,
                              hipStream_t stream) {
  const float* nf    = (const float*)d_in[0];
  const int*   src   = (const int*)d_in[1];
  const int*   dst   = (const int*)d_in[2];
  const float* W1    = (const float*)d_in[3];
  const float* b1    = (const float*)d_in[4];
  const float* W2    = (const float*)d_in[5];
  const float* b2    = (const float*)d_in[6];
  const float* Ws1   = (const float*)d_in[7];
  const float* Ws2   = (const float*)d_in[8];
  const float* gamma = (const float*)d_in[9];
  const float* beta  = (const float*)d_in[10];
  float* out = (float*)d_out;

  // ws layout (~114 MB):
  //   S      : RR*NN*4 f32   (6.4 MB)
  //   off    : RR*(NN+1) int (1.6 MB)   CSR offsets
  //   cursor : RR*NN int     (1.6 MB)   node fill cursors
  //   bsum   : RR*NB int                scan block sums
  //   gcur   : RR*NB int                coarse-bucket cursors
  //   pairs  : RR*EE int2    (51.2 MB)  coarse-binned (dst,src); dead after
  //            k_place -> REUSED as nf16 (NN*64 u32 = 25.6 MB per relation)
  //   sorted : RR*EE int     (25.6 MB)  src grouped by dst
  float* S      = (float*)d_ws;
  int*   off    = (int*)(S + (size_t)RR * NN * 4);
  int*   cursor = off + (size_t)RR * (NN + 1);
  int*   bsum   = cursor + (size_t)RR * NN;
  int*   gcur   = bsum + (size_t)RR * NB;
  int2*  pairs  = (int2*)(gcur + (size_t)RR * NB);
  int*   sorted = (int*)(pairs + (size_t)RR * EE);
  u32*   nf16   = (u32*)pairs;   // alias: valid only after k_place

  hipMemsetAsync(off, 0, (size_t)RR * (NN + 1) * sizeof(int), stream);
  {
    dim3 grid((EE + 255) / 256, RR);
    k_hist<<<grid, dim3(256), 0, stream>>>(dst, off);
  }
  k_scan1<<<dim3(NB, RR), dim3(1024), 0, stream>>>(off, bsum);
  k_scan2<<<dim3(RR), dim3(128), 0, stream>>>(bsum);
  k_scan3<<<dim3(NB, RR), dim3(1024), 0, stream>>>(off, bsum, cursor);
  k_initg<<<dim3((RR * NB + 255) / 256), dim3(256), 0, stream>>>(off, gcur);
  {
    dim3 grid((EE + CHUNK - 1) / CHUNK, RR);
    k_bin<<<grid, dim3(256), 0, stream>>>(src, dst, gcur, pairs);
  }
  k_place<<<dim3(NB, RR), dim3(256), 0, stream>>>(pairs, off, cursor, sorted);
  for (int r = 0; r < RR; ++r) {
    k_cvt<<<dim3((unsigned)(((long)NN * 64 + 255) / 256)), dim3(256), 0, stream>>>(nf, nf16, r);
    dim3 grid((NN + TN - 1) / TN);
    k_mlp<<<grid, dim3(BLK), 0, stream>>>(nf, nf16, W1, b1, W2, b2, Ws1, Ws2,
                                          gamma, beta, off, sorted, S, out, r);
  }
  {
    const long blocks = ((long)NN + 3) / 4;  // 1 wave/node
    k_combine<<<dim3((unsigned)blocks), dim3(256), 0, stream>>>(S, out);
  }
}

// Round 12
// 1628.576 us; speedup vs baseline: 1.3226x; 1.3226x over previous
//
#include <hip/hip_runtime.h>
#include <stdint.h>

#define NN 100000
#define RR 4
#define EE 1600000
#define DD 128
#define TN 32
#define BLK 256
#define NB 98     // ceil((NN+1)/1024) scan blocks; ALSO # of 1024-node buckets
#define CHUNK 2048

typedef unsigned int u32;
typedef unsigned short u16;

__device__ __forceinline__ u16 f2bf(float f) {
  union { float f; u32 i; } c; c.f = f;
  const u32 lsb = (c.i >> 16) & 1u;
  c.i += 0x7fffu + lsb;  // round-to-nearest-even
  return (u16)(c.i >> 16);
}
__device__ __forceinline__ u32 pack2(float a, float b) {
  return (u32)f2bf(a) | ((u32)f2bf(b) << 16);
}
__device__ __forceinline__ float u2f(u32 u) {
  union { u32 i; float f; } c; c.i = u; return c.f;
}

// ---------- pass 1: histogram of dst (offsets shifted by +1) ----------
__global__ __launch_bounds__(256)
void k_hist(const int* __restrict__ dst, int* __restrict__ off) {
  const int r = blockIdx.y;
  const long e = (long)blockIdx.x * 256 + threadIdx.x;
  if (e >= EE) return;
  const int d = dst[(size_t)r * EE + e];
  atomicAdd(&off[(size_t)r * (NN + 1) + d + 1], 1);
}

// ---------- pass 2a: block-local inclusive scan ----------
__global__ __launch_bounds__(1024)
void k_scan1(int* __restrict__ off, int* __restrict__ bsum) {
  const int r = blockIdx.y;
  int* a = off + (size_t)r * (NN + 1);
  __shared__ int tmp[1024];
  const int t = threadIdx.x;
  const int idx = blockIdx.x * 1024 + t;
  tmp[t] = (idx <= NN) ? a[idx] : 0;
  __syncthreads();
  for (int o = 1; o < 1024; o <<= 1) {
    const int y = (t >= o) ? tmp[t - o] : 0;
    __syncthreads();
    tmp[t] += y;
    __syncthreads();
  }
  if (idx <= NN) a[idx] = tmp[t];
  if (t == 1023) bsum[r * NB + blockIdx.x] = tmp[1023];
}

// ---------- pass 2b: scan the 98 block sums -> exclusive prefix ----------
__global__ __launch_bounds__(128)
void k_scan2(int* __restrict__ bsum) {
  const int r = blockIdx.x;
  __shared__ int tmp[128];
  const int t = threadIdx.x;
  const int v = (t < NB) ? bsum[r * NB + t] : 0;
  tmp[t] = v;
  __syncthreads();
  for (int o = 1; o < 128; o <<= 1) {
    const int y = (t >= o) ? tmp[t - o] : 0;
    __syncthreads();
    tmp[t] += y;
    __syncthreads();
  }
  if (t < NB) bsum[r * NB + t] = tmp[t] - v;  // exclusive
}

// ---------- pass 2c: add block prefix; emit cursor copy ----------
__global__ __launch_bounds__(1024)
void k_scan3(int* __restrict__ off, const int* __restrict__ bsum,
             int* __restrict__ cursor) {
  const int r = blockIdx.y;
  const int idx = blockIdx.x * 1024 + threadIdx.x;
  const int add = bsum[r * NB + blockIdx.x];
  int* a = off + (size_t)r * (NN + 1);
  if (idx <= NN) {
    const int v = a[idx] + add;
    a[idx] = v;
    if (idx < NN) cursor[(size_t)r * NN + idx] = v;
  }
}

// ---------- init coarse-bucket cursors from CSR offsets ----------
__global__ __launch_bounds__(256)
void k_initg(const int* __restrict__ off, int* __restrict__ gcur) {
  const int i = blockIdx.x * 256 + threadIdx.x;
  if (i < RR * NB) {
    const int r = i / NB, b = i % NB;
    gcur[i] = off[(size_t)r * (NN + 1) + (b << 10)];
  }
}

// ---------- pass 3a: coarse binning with LDS-staged dense writes ----------
__global__ __launch_bounds__(256)
void k_bin(const int* __restrict__ src, const int* __restrict__ dst,
           int* __restrict__ gcur, int2* __restrict__ pairs) {
  const int r = blockIdx.y;
  const long base = (long)blockIdx.x * CHUNK;
  const int t = threadIdx.x;
  __shared__ int hist[NB], lofs[NB], gbase[NB], hcur[NB];
  __shared__ int2 stage[CHUNK];  // 16 KB
  for (int i = t; i < NB; i += 256) hist[i] = 0;
  __syncthreads();
  int d[8], s[8];
#pragma unroll
  for (int k = 0; k < 8; ++k) {
    const long e = base + k * 256 + t;
    if (e < EE) {
      d[k] = dst[(size_t)r * EE + e];
      s[k] = src[(size_t)r * EE + e];
      atomicAdd(&hist[d[k] >> 10], 1);
    } else d[k] = -1;
  }
  __syncthreads();
  if (t == 0) {
    int run = 0;
    for (int b = 0; b < NB; ++b) { lofs[b] = run; run += hist[b]; }
  }
  __syncthreads();
  if (t < NB) {
    hcur[t] = 0;
    gbase[t] = hist[t] ? atomicAdd(&gcur[r * NB + t], hist[t]) : 0;
  }
  __syncthreads();
#pragma unroll
  for (int k = 0; k < 8; ++k) {
    if (d[k] >= 0) {
      const int b = d[k] >> 10;
      const int slot = lofs[b] + atomicAdd(&hcur[b], 1);
      stage[slot] = make_int2(d[k], s[k]);
    }
  }
  __syncthreads();
  const int total = (int)((EE - base < CHUNK) ? (EE - base) : CHUNK);
  for (int i = t; i < total; i += 256) {
    const int2 p = stage[i];
    const int b = p.x >> 10;
    pairs[(size_t)r * EE + gbase[b] + (i - lofs[b])] = p;
  }
}

// ---------- pass 3b: exact placement within L2-resident bucket window ----------
__global__ __launch_bounds__(256)
void k_place(const int2* __restrict__ pairs, const int* __restrict__ off,
             int* __restrict__ cursor, int* __restrict__ sorted) {
  const int r = blockIdx.y;
  const int b = blockIdx.x;
  const int nlo = b << 10;
  const int nhi = (nlo + 1024 < NN) ? nlo + 1024 : NN;
  const int span0 = off[(size_t)r * (NN + 1) + nlo];
  const int span1 = off[(size_t)r * (NN + 1) + nhi];
  for (int i = span0 + threadIdx.x; i < span1; i += 256) {
    const int2 p = pairs[(size_t)r * EE + i];
    const int pos = atomicAdd(&cursor[(size_t)r * NN + p.x], 1);
    sorted[(size_t)r * EE + pos] = p.y;
  }
}

// ---------- convert one relation's features to packed bf16 rows ----------
// nf16[n*64 + lane] holds dims {2*lane, 2*lane+1} of node n as bf16x2.
// Runs AFTER k_place; nf16 aliases the dead `pairs` region.
__global__ __launch_bounds__(256)
void k_cvt(const float* __restrict__ nf, u32* __restrict__ nf16, int r) {
  const long t = (long)blockIdx.x * 256 + threadIdx.x;
  if (t >= (long)NN * 64) return;
  const int n = (int)(t >> 6);
  const int l = (int)(t & 63);
  const float2 v = *(const float2*)(nf + ((size_t)n * RR + r) * DD + l * 2);
  nf16[t] = pack2(v.x, v.y);
}

// ---------- pre-convert weights to packed bf16 ----------
// w16 layout: [mat][8192] u32 pairs; mat 0=W1, 1=W2, 2..5=Ws1[r]
__global__ __launch_bounds__(256)
void k_wcvt(const float* __restrict__ W1, const float* __restrict__ W2,
            const float* __restrict__ Ws1, u32* __restrict__ w16) {
  const int i = blockIdx.x * 256 + threadIdx.x;
  if (i >= 6 * 8192) return;
  const int m = i >> 13;
  const int p = i & 8191;
  const float* srcm = (m == 0) ? W1 : (m == 1) ? W2 : Ws1 + (size_t)(m - 2) * DD * DD;
  const float2 v = *(const float2*)(srcm + (size_t)p * 2);
  w16[i] = pack2(v.x, v.y);
}

// ---- copy one 64-row half of a bf16-packed 128x128 weight into LDS (16 KB) ----
__device__ __forceinline__ void loadWh16(const u32* __restrict__ Wsrc, int half,
                                         u32* __restrict__ sW16, int tid) {
  const uint4* src = (const uint4*)(Wsrc + (size_t)half * 64 * 64);
  uint4* dstv = (uint4*)sW16;
#pragma unroll
  for (int k = 0; k < 4; ++k) dstv[tid + k * BLK] = src[tid + k * BLK];  // 1024 uint4
}

// ---- 4x4-blocked half-K gemm with bf16-packed weights ----
// Per k-quad: 4 ds_read_b128 (A) + 4 ds_read_b64 (W pairs) + 16 unpack VALU + 64 FMA.
__device__ __forceinline__ void gemm4x4(const float (*__restrict__ in)[DD],
                                        const u32* __restrict__ sW16,
                                        int rg, int c2, int kbase, float acc[4][4]) {
  for (int k4 = 0; k4 < 64; k4 += 4) {
    const float4 a0 = *(const float4*)(&in[rg + 0][kbase + k4]);
    const float4 a1 = *(const float4*)(&in[rg + 1][kbase + k4]);
    const float4 a2 = *(const float4*)(&in[rg + 2][kbase + k4]);
    const float4 a3 = *(const float4*)(&in[rg + 3][kbase + k4]);
    const uint2 p0 = *(const uint2*)(&sW16[(k4 + 0) * 64 + c2]);
    const uint2 p1 = *(const uint2*)(&sW16[(k4 + 1) * 64 + c2]);
    const uint2 p2 = *(const uint2*)(&sW16[(k4 + 2) * 64 + c2]);
    const uint2 p3 = *(const uint2*)(&sW16[(k4 + 3) * 64 + c2]);
    const float4 w0 = make_float4(u2f(p0.x << 16), u2f(p0.x & 0xffff0000u),
                                  u2f(p0.y << 16), u2f(p0.y & 0xffff0000u));
    const float4 w1 = make_float4(u2f(p1.x << 16), u2f(p1.x & 0xffff0000u),
                                  u2f(p1.y << 16), u2f(p1.y & 0xffff0000u));
    const float4 w2 = make_float4(u2f(p2.x << 16), u2f(p2.x & 0xffff0000u),
                                  u2f(p2.y << 16), u2f(p2.y & 0xffff0000u));
    const float4 w3 = make_float4(u2f(p3.x << 16), u2f(p3.x & 0xffff0000u),
                                  u2f(p3.y << 16), u2f(p3.y & 0xffff0000u));
#define ROWF(i, ai)                                                                               \
    acc[i][0] = fmaf(ai.x, w0.x, fmaf(ai.y, w1.x, fmaf(ai.z, w2.x, fmaf(ai.w, w3.x, acc[i][0])))); \
    acc[i][1] = fmaf(ai.x, w0.y, fmaf(ai.y, w1.y, fmaf(ai.z, w2.y, fmaf(ai.w, w3.y, acc[i][1])))); \
    acc[i][2] = fmaf(ai.x, w0.z, fmaf(ai.y, w1.z, fmaf(ai.z, w2.z, fmaf(ai.w, w3.z, acc[i][2])))); \
    acc[i][3] = fmaf(ai.x, w0.w, fmaf(ai.y, w1.w, fmaf(ai.z, w2.w, fmaf(ai.w, w3.w, acc[i][3]))));
    ROWF(0, a0) ROWF(1, a1) ROWF(2, a2) ROWF(3, a3)
#undef ROWF
  }
}

// ------- fused: bf16 gather(CSR) + residual + MLP + LN + attention scores -------
__global__ __launch_bounds__(BLK, 5)
void k_mlp(const float* __restrict__ nf, const u32* __restrict__ nf16,
           const u32* __restrict__ w16, const float* __restrict__ b1,
           const float* __restrict__ b2, const float* __restrict__ Ws2,
           const float* __restrict__ gamma, const float* __restrict__ beta,
           const int* __restrict__ off, const int* __restrict__ sortedSrc,
           float* __restrict__ S, float* __restrict__ out, int r) {
  __shared__ float sA[TN][DD];                   // 16 KB
  __shared__ __align__(16) u32 sW16[64 * 64];    // 16 KB  (total 32 KB -> 5 blocks/CU)

  const int tid = threadIdx.x;
  const int n0 = blockIdx.x * TN;
  const int rg = (tid >> 5) * 4;   // 8 row groups of 4
  const int c4 = (tid & 31) * 4;   // 32 col groups of 4
  const int c2 = c4 >> 1;          // u32-pair column index

  const u32* Wg1 = w16;
  const u32* Wg2 = w16 + 8192;
  const u32* Wg3 = w16 + (size_t)(2 + r) * 8192;

  // ---- stage rst = feat(f32) + bf16-gather(CSR) -> sA; wave owns 8 rows ----
  {
    const int wv = tid >> 6;
    const int lane = tid & 63;
    const int* ss = sortedSrc + (size_t)r * EE;
#pragma unroll
    for (int q = 0; q < 8; ++q) {
      const int i = wv * 8 + q;
      const int n = n0 + i;
      float2 a2 = make_float2(0.f, 0.f);
      if (n < NN) {
        a2 = *(const float2*)(nf + ((size_t)n * RR + r) * DD + lane * 2);
        const int e1 = off[(size_t)r * (NN + 1) + n + 1];
        int e = off[(size_t)r * (NN + 1) + n];
        for (; e + 7 < e1; e += 8) {  // unroll-8: 8 bf16 rows in flight
          u32 v[8];
#pragma unroll
          for (int k = 0; k < 8; ++k)
            v[k] = nf16[((size_t)ss[e + k] << 6) + lane];
#pragma unroll
          for (int k = 0; k < 8; ++k) {
            a2.x += u2f(v[k] << 16);
            a2.y += u2f(v[k] & 0xffff0000u);
          }
        }
        for (; e < e1; ++e) {
          const u32 v = nf16[((size_t)ss[e] << 6) + lane];
          a2.x += u2f(v << 16);
          a2.y += u2f(v & 0xffff0000u);
        }
      }
      *(float2*)(&sA[i][lane * 2]) = a2;
    }
  }
  loadWh16(Wg1, 0, sW16, tid);
  __syncthreads();

  float acc[4][4];
#pragma unroll
  for (int i = 0; i < 4; ++i)
#pragma unroll
    for (int jj = 0; jj < 4; ++jj) acc[i][jj] = 0.f;

  // ---- GEMM1 ----
  gemm4x4(sA, sW16, rg, c2, 0, acc);
  __syncthreads();
  loadWh16(Wg1, 1, sW16, tid);
  __syncthreads();
  gemm4x4(sA, sW16, rg, c2, 64, acc);
  __syncthreads();
  {
    const float4 bb = *(const float4*)(&b1[c4]);
#pragma unroll
    for (int i = 0; i < 4; ++i)
      *(float4*)(&sA[rg + i][c4]) = make_float4(
          fmaxf(acc[i][0] + bb.x, 0.f), fmaxf(acc[i][1] + bb.y, 0.f),
          fmaxf(acc[i][2] + bb.z, 0.f), fmaxf(acc[i][3] + bb.w, 0.f));
  }
  loadWh16(Wg2, 0, sW16, tid);
  __syncthreads();

  // ---- GEMM2 ----
#pragma unroll
  for (int i = 0; i < 4; ++i)
#pragma unroll
    for (int jj = 0; jj < 4; ++jj) acc[i][jj] = 0.f;
  gemm4x4(sA, sW16, rg, c2, 0, acc);
  __syncthreads();
  loadWh16(Wg2, 1, sW16, tid);
  __syncthreads();
  gemm4x4(sA, sW16, rg, c2, 64, acc);
  __syncthreads();
  {
    const float4 bb = *(const float4*)(&b2[c4]);
#pragma unroll
    for (int i = 0; i < 4; ++i)
      *(float4*)(&sA[rg + i][c4]) = make_float4(
          fmaxf(acc[i][0] + bb.x, 0.f), fmaxf(acc[i][1] + bb.y, 0.f),
          fmaxf(acc[i][2] + bb.z, 0.f), fmaxf(acc[i][3] + bb.w, 0.f));
  }
  loadWh16(Wg3, 0, sW16, tid);
  __syncthreads();

  // ---- LayerNorm (8 threads/row, stats in registers via shfl) ----
  {
    const int i = tid >> 3;          // 0..31
    const int c0 = (tid & 7) * 16;
    float s = 0.f, s2 = 0.f;
    float hv[16];
#pragma unroll
    for (int c = 0; c < 16; ++c) {
      const float v = sA[i][c0 + c];
      hv[c] = v;
      s += v; s2 += v * v;
    }
#pragma unroll
    for (int off2 = 1; off2 < 8; off2 <<= 1) {
      s  += __shfl_xor(s, off2);
      s2 += __shfl_xor(s2, off2);
    }
    const float mu = s * (1.f / 128.f);
    const float var = fmaxf(s2 * (1.f / 128.f) - mu * mu, 0.f);
    const float rs = rsqrtf(var + 1e-5f);
    const int n = n0 + i;
#pragma unroll
    for (int c = 0; c < 16; ++c) {
      hv[c] = (hv[c] - mu) * rs * gamma[c0 + c] + beta[c0 + c];
      sA[i][c0 + c] = hv[c];   // own slice only: no cross-thread hazard
    }
    if (n < NN) {
      float4* op = (float4*)(out + ((size_t)n * RR + r) * DD + c0);
#pragma unroll
      for (int q = 0; q < 4; ++q)
        op[q] = make_float4(hv[q * 4], hv[q * 4 + 1], hv[q * 4 + 2], hv[q * 4 + 3]);
    }
  }
  __syncthreads();

  // ---- GEMM3: tanh(h @ Ws1[r]) ----
#pragma unroll
  for (int i = 0; i < 4; ++i)
#pragma unroll
    for (int jj = 0; jj < 4; ++jj) acc[i][jj] = 0.f;
  gemm4x4(sA, sW16, rg, c2, 0, acc);
  __syncthreads();
  loadWh16(Wg3, 1, sW16, tid);
  __syncthreads();
  gemm4x4(sA, sW16, rg, c2, 64, acc);
  __syncthreads();
#pragma unroll
  for (int i = 0; i < 4; ++i)
    *(float4*)(&sA[rg + i][c4]) = make_float4(
        tanhf(acc[i][0]), tanhf(acc[i][1]), tanhf(acc[i][2]), tanhf(acc[i][3]));
  {
    float* sWs2 = (float*)sW16;   // 512 f32 = 2 KB, reuse LDS
    sWs2[tid]       = Ws2[(size_t)r * 512 + tid];
    sWs2[tid + 256] = Ws2[(size_t)r * 512 + tid + 256];
  }
  __syncthreads();

  // ---- scores = tanh(...) @ Ws2[r] -> S ----
  if (tid < TN * 4) {
    const float* sWs2 = (const float*)sW16;
    const int i = tid >> 2;
    const int k = tid & 3;
    float a = 0.f;
#pragma unroll 8
    for (int q = 0; q < DD; ++q) a = fmaf(sA[i][q], sWs2[q * 4 + k], a);
    const int n = n0 + i;
    if (n < NN) S[((size_t)r * NN + n) * 4 + k] = a;
  }
}

// -------- softmax over relations + final mix (in place on out) --------
__global__ __launch_bounds__(256)
void k_combine(const float* __restrict__ S, float* __restrict__ out) {
  const long gw = (((long)blockIdx.x * 256) + threadIdx.x) >> 6;
  const int lane = threadIdx.x & 63;
  if (gw >= NN) return;
  const int n = (int)gw;
  float a[4][4];
#pragma unroll
  for (int r = 0; r < 4; ++r)
#pragma unroll
    for (int k = 0; k < 4; ++k)
      a[r][k] = S[((size_t)r * NN + n) * 4 + k];
#pragma unroll
  for (int k = 0; k < 4; ++k) {
    const float m = fmaxf(fmaxf(a[0][k], a[1][k]), fmaxf(a[2][k], a[3][k]));
    const float e0 = expf(a[0][k] - m);
    const float e1 = expf(a[1][k] - m);
    const float e2 = expf(a[2][k] - m);
    const float e3 = expf(a[3][k] - m);
    const float inv = 1.f / (e0 + e1 + e2 + e3);
    a[0][k] = e0 * inv; a[1][k] = e1 * inv; a[2][k] = e2 * inv; a[3][k] = e3 * inv;
  }
  float2 hv[4];
#pragma unroll
  for (int k = 0; k < 4; ++k)
    hv[k] = *(const float2*)(out + ((size_t)n * RR + k) * DD + lane * 2);
#pragma unroll
  for (int r = 0; r < 4; ++r) {
    float2 o;
    o.x = a[r][0] * hv[0].x + a[r][1] * hv[1].x + a[r][2] * hv[2].x + a[r][3] * hv[3].x;
    o.y = a[r][0] * hv[0].y + a[r][1] * hv[1].y + a[r][2] * hv[2].y + a[r][3] * hv[3].y;
    *(float2*)(out + ((size_t)n * RR + r) * DD + lane * 2) = o;
  }
}

extern "C" void kernel_launch(void* const* d_in, const int* in_sizes, int n_in,
                              void* d_out, int out_size, void* d_ws, size_t ws_size,
                              hipStream_t stream) {
  const float* nf    = (const float*)d_in[0];
  const int*   src   = (const int*)d_in[1];
  const int*   dst   = (const int*)d_in[2];
  const float* W1    = (const float*)d_in[3];
  const float* b1    = (const float*)d_in[4];
  const float* W2    = (const float*)d_in[5];
  const float* b2    = (const float*)d_in[6];
  const float* Ws1   = (const float*)d_in[7];
  const float* Ws2   = (const float*)d_in[8];
  const float* gamma = (const float*)d_in[9];
  const float* beta  = (const float*)d_in[10];
  float* out = (float*)d_out;

  // ws layout (~87 MB):
  //   S      : RR*NN*4 f32   (6.4 MB)
  //   off    : RR*(NN+1) int (1.6 MB)
  //   cursor : RR*NN int     (1.6 MB)
  //   bsum   : RR*NB int
  //   gcur   : RR*NB int
  //   w16    : 6*8192 u32    (0.2 MB)  bf16-packed W1,W2,Ws1[0..3]
  //   pairs  : RR*EE int2    (51.2 MB) dead after k_place -> nf16 alias
  //   sorted : RR*EE int     (25.6 MB)
  float* S      = (float*)d_ws;
  int*   off    = (int*)(S + (size_t)RR * NN * 4);
  int*   cursor = off + (size_t)RR * (NN + 1);
  int*   bsum   = cursor + (size_t)RR * NN;
  int*   gcur   = bsum + (size_t)RR * NB;
  u32*   w16    = (u32*)(gcur + (size_t)RR * NB);
  int2*  pairs  = (int2*)(w16 + (size_t)6 * 8192);
  int*   sorted = (int*)(pairs + (size_t)RR * EE);
  u32*   nf16   = (u32*)pairs;   // alias: valid only after k_place

  hipMemsetAsync(off, 0, (size_t)RR * (NN + 1) * sizeof(int), stream);
  k_wcvt<<<dim3(192), dim3(256), 0, stream>>>(W1, W2, Ws1, w16);
  {
    dim3 grid((EE + 255) / 256, RR);
    k_hist<<<grid, dim3(256), 0, stream>>>(dst, off);
  }
  k_scan1<<<dim3(NB, RR), dim3(1024), 0, stream>>>(off, bsum);
  k_scan2<<<dim3(RR), dim3(128), 0, stream>>>(bsum);
  k_scan3<<<dim3(NB, RR), dim3(1024), 0, stream>>>(off, bsum, cursor);
  k_initg<<<dim3((RR * NB + 255) / 256), dim3(256), 0, stream>>>(off, gcur);
  {
    dim3 grid((EE + CHUNK - 1) / CHUNK, RR);
    k_bin<<<grid, dim3(256), 0, stream>>>(src, dst, gcur, pairs);
  }
  k_place<<<dim3(NB, RR), dim3(256), 0, stream>>>(pairs, off, cursor, sorted);
  for (int r = 0; r < RR; ++r) {
    k_cvt<<<dim3((unsigned)(((long)NN * 64 + 255) / 256)), dim3(256), 0, stream>>>(nf, nf16, r);
    dim3 grid((NN + TN - 1) / TN);
    k_mlp<<<grid, dim3(BLK), 0, stream>>>(nf, nf16, w16, b1, b2, Ws2,
                                          gamma, beta, off, sorted, S, out, r);
  }
  {
    const long blocks = ((long)NN + 3) / 4;  // 1 wave/node
    k_combine<<<dim3((unsigned)blocks), dim3(256), 0, stream>>>(S, out);
  }
}

// Round 13
// 1306.731 us; speedup vs baseline: 1.6484x; 1.2463x over previous
//
#include <hip/hip_runtime.h>
#include <stdint.h>

#define NN 100000
#define RR 4
#define EE 1600000
#define DD 128
#define TN 32
#define BLK 256
#define NB 98     // ceil(NN/1024) 1024-node buckets
#define CHUNK 2048

typedef unsigned int u32;
typedef unsigned short u16;

__device__ __forceinline__ u16 f2bf(float f) {
  union { float f; u32 i; } c; c.f = f;
  const u32 lsb = (c.i >> 16) & 1u;
  c.i += 0x7fffu + lsb;  // round-to-nearest-even
  return (u16)(c.i >> 16);
}
__device__ __forceinline__ u32 pack2(float a, float b) {
  return (u32)f2bf(a) | ((u32)f2bf(b) << 16);
}
__device__ __forceinline__ float u2f(u32 u) {
  union { u32 i; float f; } c; c.i = u; return c.f;
}

// ---------- pass 1: per-chunk LDS bucket histogram -> global bucket counts ----------
__global__ __launch_bounds__(256)
void k_cnt(const int* __restrict__ dst, int* __restrict__ cnt) {
  const int r = blockIdx.y;
  const long base = (long)blockIdx.x * CHUNK;
  const int t = threadIdx.x;
  __shared__ int hist[NB];
  for (int i = t; i < NB; i += 256) hist[i] = 0;
  __syncthreads();
#pragma unroll
  for (int k = 0; k < 8; ++k) {
    const long e = base + k * 256 + t;
    if (e < EE) atomicAdd(&hist[dst[(size_t)r * EE + e] >> 10], 1);
  }
  __syncthreads();
  if (t < NB && hist[t]) atomicAdd(&cnt[r * NB + t], hist[t]);
}

// ---------- pass 2: scan 4x98 bucket counts -> bucket bases + bin cursors ----------
__global__ __launch_bounds__(512)
void k_bscan(const int* __restrict__ cnt, int* __restrict__ bOff, int* __restrict__ gcur) {
  __shared__ int tmp[512];
  const int t = threadIdx.x;
  const int r = t >> 7, b = t & 127;
  const int v = (b < NB) ? cnt[r * NB + b] : 0;
  tmp[t] = v;
  __syncthreads();
  for (int o = 1; o < 128; o <<= 1) {
    const int y = (b >= o) ? tmp[t - o] : 0;
    __syncthreads();
    tmp[t] += y;
    __syncthreads();
  }
  if (b < NB) {
    const int excl = tmp[t] - v;
    bOff[r * (NB + 1) + b] = excl;
    gcur[r * NB + b] = excl;
    if (b == NB - 1) bOff[r * (NB + 1) + NB] = tmp[t];
  }
}

// ---------- pass 3: coarse binning with LDS-staged dense writes ----------
__global__ __launch_bounds__(256)
void k_bin(const int* __restrict__ src, const int* __restrict__ dst,
           int* __restrict__ gcur, int2* __restrict__ pairs) {
  const int r = blockIdx.y;
  const long base = (long)blockIdx.x * CHUNK;
  const int t = threadIdx.x;
  __shared__ int hist[NB], lofs[NB], gbase[NB], hcur[NB];
  __shared__ int2 stage[CHUNK];  // 16 KB
  for (int i = t; i < NB; i += 256) hist[i] = 0;
  __syncthreads();
  int d[8], s[8];
#pragma unroll
  for (int k = 0; k < 8; ++k) {
    const long e = base + k * 256 + t;
    if (e < EE) {
      d[k] = dst[(size_t)r * EE + e];
      s[k] = src[(size_t)r * EE + e];
      atomicAdd(&hist[d[k] >> 10], 1);
    } else d[k] = -1;
  }
  __syncthreads();
  if (t == 0) {
    int run = 0;
    for (int b = 0; b < NB; ++b) { lofs[b] = run; run += hist[b]; }
  }
  __syncthreads();
  if (t < NB) {
    hcur[t] = 0;
    gbase[t] = hist[t] ? atomicAdd(&gcur[r * NB + t], hist[t]) : 0;
  }
  __syncthreads();
#pragma unroll
  for (int k = 0; k < 8; ++k) {
    if (d[k] >= 0) {
      const int b = d[k] >> 10;
      const int slot = lofs[b] + atomicAdd(&hcur[b], 1);
      stage[slot] = make_int2(d[k], s[k]);
    }
  }
  __syncthreads();
  const int total = (int)((EE - base < CHUNK) ? (EE - base) : CHUNK);
  for (int i = t; i < total; i += 256) {
    const int2 p = stage[i];
    const int b = p.x >> 10;
    pairs[(size_t)r * EE + gbase[b] + (i - lofs[b])] = p;
  }
}

// ---------- pass 4: in-bucket CSR build + placement, all LDS atomics ----------
__global__ __launch_bounds__(256)
void k_place(const int2* __restrict__ pairs, const int* __restrict__ bOff,
             int* __restrict__ off, int* __restrict__ sorted) {
  const int r = blockIdx.y;
  const int b = blockIdx.x;
  const int nlo = b << 10;
  const int span0 = bOff[r * (NB + 1) + b];
  const int span1 = bOff[r * (NB + 1) + b + 1];
  const int t = threadIdx.x;
  __shared__ __align__(16) int ncnt[1024];
  __shared__ int part[256];
  ((int4*)ncnt)[t] = make_int4(0, 0, 0, 0);
  __syncthreads();
  for (int i = span0 + t; i < span1; i += 256)
    atomicAdd(&ncnt[pairs[(size_t)r * EE + i].x - nlo], 1);
  __syncthreads();
  // exclusive scan of ncnt[1024] (4 elems/thread + 256-wide scan)
  const int4 c = ((int4*)ncnt)[t];
  const int s = c.x + c.y + c.z + c.w;
  part[t] = s;
  __syncthreads();
  for (int o = 1; o < 256; o <<= 1) {
    const int y = (t >= o) ? part[t - o] : 0;
    __syncthreads();
    part[t] += y;
    __syncthreads();
  }
  const int base = part[t] - s;
  int ex[4];
  ex[0] = base;
  ex[1] = base + c.x;
  ex[2] = base + c.x + c.y;
  ex[3] = base + c.x + c.y + c.z;
  ((int4*)ncnt)[t] = make_int4(ex[0], ex[1], ex[2], ex[3]);
#pragma unroll
  for (int j = 0; j < 4; ++j) {
    const int n = nlo + t * 4 + j;
    if (n < NN) off[(size_t)r * (NN + 1) + n] = span0 + ex[j];
  }
  if (b == NB - 1 && t == 0) off[(size_t)r * (NN + 1) + NN] = span1;
  __syncthreads();
  for (int i = span0 + t; i < span1; i += 256) {
    const int2 p = pairs[(size_t)r * EE + i];
    const int pos = atomicAdd(&ncnt[p.x - nlo], 1);
    sorted[(size_t)r * EE + span0 + pos] = p.y;
  }
}

// ---------- convert ALL relations' features to packed bf16 rows ----------
// nf16[r][n*64 + lane] holds dims {2*lane, 2*lane+1} of node n as bf16x2.
// Runs AFTER k_place; aliases the dead `pairs` region (+51.2 MB beyond).
__global__ __launch_bounds__(256)
void k_cvt(const float* __restrict__ nf, u32* __restrict__ nf16) {
  const int r = blockIdx.y;
  const long t = (long)blockIdx.x * 256 + threadIdx.x;
  if (t >= (long)NN * 64) return;
  const int n = (int)(t >> 6);
  const int l = (int)(t & 63);
  const float2 v = *(const float2*)(nf + ((size_t)n * RR + r) * DD + l * 2);
  nf16[(size_t)r * NN * 64 + t] = pack2(v.x, v.y);
}

// ---------- pre-convert weights to packed bf16 ----------
// w16 layout: [mat][8192] u32 pairs; mat 0=W1, 1=W2, 2..5=Ws1[r]
__global__ __launch_bounds__(256)
void k_wcvt(const float* __restrict__ W1, const float* __restrict__ W2,
            const float* __restrict__ Ws1, u32* __restrict__ w16) {
  const int i = blockIdx.x * 256 + threadIdx.x;
  if (i >= 6 * 8192) return;
  const int m = i >> 13;
  const int p = i & 8191;
  const float* srcm = (m == 0) ? W1 : (m == 1) ? W2 : Ws1 + (size_t)(m - 2) * DD * DD;
  const float2 v = *(const float2*)(srcm + (size_t)p * 2);
  w16[i] = pack2(v.x, v.y);
}

// ---- copy one 64-row half of a bf16-packed 128x128 weight into LDS (16 KB) ----
__device__ __forceinline__ void loadWh16(const u32* __restrict__ Wsrc, int half,
                                         u32* __restrict__ sW16, int tid) {
  const uint4* src = (const uint4*)(Wsrc + (size_t)half * 64 * 64);
  uint4* dstv = (uint4*)sW16;
#pragma unroll
  for (int k = 0; k < 4; ++k) dstv[tid + k * BLK] = src[tid + k * BLK];  // 1024 uint4
}

// ---- 4x4-blocked half-K gemm with bf16-packed weights ----
__device__ __forceinline__ void gemm4x4(const float (*__restrict__ in)[DD],
                                        const u32* __restrict__ sW16,
                                        int rg, int c2, int kbase, float acc[4][4]) {
  for (int k4 = 0; k4 < 64; k4 += 4) {
    const float4 a0 = *(const float4*)(&in[rg + 0][kbase + k4]);
    const float4 a1 = *(const float4*)(&in[rg + 1][kbase + k4]);
    const float4 a2 = *(const float4*)(&in[rg + 2][kbase + k4]);
    const float4 a3 = *(const float4*)(&in[rg + 3][kbase + k4]);
    const uint2 p0 = *(const uint2*)(&sW16[(k4 + 0) * 64 + c2]);
    const uint2 p1 = *(const uint2*)(&sW16[(k4 + 1) * 64 + c2]);
    const uint2 p2 = *(const uint2*)(&sW16[(k4 + 2) * 64 + c2]);
    const uint2 p3 = *(const uint2*)(&sW16[(k4 + 3) * 64 + c2]);
    const float4 w0 = make_float4(u2f(p0.x << 16), u2f(p0.x & 0xffff0000u),
                                  u2f(p0.y << 16), u2f(p0.y & 0xffff0000u));
    const float4 w1 = make_float4(u2f(p1.x << 16), u2f(p1.x & 0xffff0000u),
                                  u2f(p1.y << 16), u2f(p1.y & 0xffff0000u));
    const float4 w2 = make_float4(u2f(p2.x << 16), u2f(p2.x & 0xffff0000u),
                                  u2f(p2.y << 16), u2f(p2.y & 0xffff0000u));
    const float4 w3 = make_float4(u2f(p3.x << 16), u2f(p3.x & 0xffff0000u),
                                  u2f(p3.y << 16), u2f(p3.y & 0xffff0000u));
#define ROWF(i, ai)                                                                               \
    acc[i][0] = fmaf(ai.x, w0.x, fmaf(ai.y, w1.x, fmaf(ai.z, w2.x, fmaf(ai.w, w3.x, acc[i][0])))); \
    acc[i][1] = fmaf(ai.x, w0.y, fmaf(ai.y, w1.y, fmaf(ai.z, w2.y, fmaf(ai.w, w3.y, acc[i][1])))); \
    acc[i][2] = fmaf(ai.x, w0.z, fmaf(ai.y, w1.z, fmaf(ai.z, w2.z, fmaf(ai.w, w3.z, acc[i][2])))); \
    acc[i][3] = fmaf(ai.x, w0.w, fmaf(ai.y, w1.w, fmaf(ai.z, w2.w, fmaf(ai.w, w3.w, acc[i][3]))));
    ROWF(0, a0) ROWF(1, a1) ROWF(2, a2) ROWF(3, a3)
#undef ROWF
  }
}

// ------- fused: bf16 gather(CSR) + residual + MLP + LN + attention scores -------
__global__ __launch_bounds__(BLK, 5)
void k_mlp(const float* __restrict__ nf, const u32* __restrict__ nf16,
           const u32* __restrict__ w16, const float* __restrict__ b1,
           const float* __restrict__ b2, const float* __restrict__ Ws2,
           const float* __restrict__ gamma, const float* __restrict__ beta,
           const int* __restrict__ off, const int* __restrict__ sortedSrc,
           float* __restrict__ S, float* __restrict__ out, int r) {
  __shared__ float sA[TN][DD];                   // 16 KB
  __shared__ __align__(16) u32 sW16[64 * 64];    // 16 KB  (total 32 KB -> 5 blocks/CU)

  const int tid = threadIdx.x;
  const int n0 = blockIdx.x * TN;
  const int rg = (tid >> 5) * 4;   // 8 row groups of 4
  const int c4 = (tid & 31) * 4;   // 32 col groups of 4
  const int c2 = c4 >> 1;          // u32-pair column index

  const u32* Wg1 = w16;
  const u32* Wg2 = w16 + 8192;
  const u32* Wg3 = w16 + (size_t)(2 + r) * 8192;

  // ---- stage rst = feat(f32) + bf16-gather(CSR) -> sA; wave owns 8 rows ----
  {
    const int wv = tid >> 6;
    const int lane = tid & 63;
    const int* ss = sortedSrc + (size_t)r * EE;
#pragma unroll
    for (int q = 0; q < 8; ++q) {
      const int i = wv * 8 + q;
      const int n = n0 + i;
      float2 a2 = make_float2(0.f, 0.f);
      if (n < NN) {
        a2 = *(const float2*)(nf + ((size_t)n * RR + r) * DD + lane * 2);
        const int e1 = off[(size_t)r * (NN + 1) + n + 1];
        int e = off[(size_t)r * (NN + 1) + n];
        for (; e + 7 < e1; e += 8) {  // unroll-8: 8 bf16 rows in flight
          u32 v[8];
#pragma unroll
          for (int k = 0; k < 8; ++k)
            v[k] = nf16[((size_t)ss[e + k] << 6) + lane];
#pragma unroll
          for (int k = 0; k < 8; ++k) {
            a2.x += u2f(v[k] << 16);
            a2.y += u2f(v[k] & 0xffff0000u);
          }
        }
        for (; e < e1; ++e) {
          const u32 v = nf16[((size_t)ss[e] << 6) + lane];
          a2.x += u2f(v << 16);
          a2.y += u2f(v & 0xffff0000u);
        }
      }
      *(float2*)(&sA[i][lane * 2]) = a2;
    }
  }
  loadWh16(Wg1, 0, sW16, tid);
  __syncthreads();

  float acc[4][4];
#pragma unroll
  for (int i = 0; i < 4; ++i)
#pragma unroll
    for (int jj = 0; jj < 4; ++jj) acc[i][jj] = 0.f;

  // ---- GEMM1 ----
  gemm4x4(sA, sW16, rg, c2, 0, acc);
  __syncthreads();
  loadWh16(Wg1, 1, sW16, tid);
  __syncthreads();
  gemm4x4(sA, sW16, rg, c2, 64, acc);
  __syncthreads();
  {
    const float4 bb = *(const float4*)(&b1[c4]);
#pragma unroll
    for (int i = 0; i < 4; ++i)
      *(float4*)(&sA[rg + i][c4]) = make_float4(
          fmaxf(acc[i][0] + bb.x, 0.f), fmaxf(acc[i][1] + bb.y, 0.f),
          fmaxf(acc[i][2] + bb.z, 0.f), fmaxf(acc[i][3] + bb.w, 0.f));
  }
  loadWh16(Wg2, 0, sW16, tid);
  __syncthreads();

  // ---- GEMM2 ----
#pragma unroll
  for (int i = 0; i < 4; ++i)
#pragma unroll
    for (int jj = 0; jj < 4; ++jj) acc[i][jj] = 0.f;
  gemm4x4(sA, sW16, rg, c2, 0, acc);
  __syncthreads();
  loadWh16(Wg2, 1, sW16, tid);
  __syncthreads();
  gemm4x4(sA, sW16, rg, c2, 64, acc);
  __syncthreads();
  {
    const float4 bb = *(const float4*)(&b2[c4]);
#pragma unroll
    for (int i = 0; i < 4; ++i)
      *(float4*)(&sA[rg + i][c4]) = make_float4(
          fmaxf(acc[i][0] + bb.x, 0.f), fmaxf(acc[i][1] + bb.y, 0.f),
          fmaxf(acc[i][2] + bb.z, 0.f), fmaxf(acc[i][3] + bb.w, 0.f));
  }
  loadWh16(Wg3, 0, sW16, tid);
  __syncthreads();

  // ---- LayerNorm (8 threads/row, stats in registers via shfl) ----
  {
    const int i = tid >> 3;          // 0..31
    const int c0 = (tid & 7) * 16;
    float s = 0.f, s2 = 0.f;
    float hv[16];
#pragma unroll
    for (int c = 0; c < 16; ++c) {
      const float v = sA[i][c0 + c];
      hv[c] = v;
      s += v; s2 += v * v;
    }
#pragma unroll
    for (int off2 = 1; off2 < 8; off2 <<= 1) {
      s  += __shfl_xor(s, off2);
      s2 += __shfl_xor(s2, off2);
    }
    const float mu = s * (1.f / 128.f);
    const float var = fmaxf(s2 * (1.f / 128.f) - mu * mu, 0.f);
    const float rs = rsqrtf(var + 1e-5f);
    const int n = n0 + i;
#pragma unroll
    for (int c = 0; c < 16; ++c) {
      hv[c] = (hv[c] - mu) * rs * gamma[c0 + c] + beta[c0 + c];
      sA[i][c0 + c] = hv[c];   // own slice only: no cross-thread hazard
    }
    if (n < NN) {
      float4* op = (float4*)(out + ((size_t)n * RR + r) * DD + c0);
#pragma unroll
      for (int q = 0; q < 4; ++q)
        op[q] = make_float4(hv[q * 4], hv[q * 4 + 1], hv[q * 4 + 2], hv[q * 4 + 3]);
    }
  }
  __syncthreads();

  // ---- GEMM3: tanh(h @ Ws1[r]) ----
#pragma unroll
  for (int i = 0; i < 4; ++i)
#pragma unroll
    for (int jj = 0; jj < 4; ++jj) acc[i][jj] = 0.f;
  gemm4x4(sA, sW16, rg, c2, 0, acc);
  __syncthreads();
  loadWh16(Wg3, 1, sW16, tid);
  __syncthreads();
  gemm4x4(sA, sW16, rg, c2, 64, acc);
  __syncthreads();
#pragma unroll
  for (int i = 0; i < 4; ++i)
    *(float4*)(&sA[rg + i][c4]) = make_float4(
        tanhf(acc[i][0]), tanhf(acc[i][1]), tanhf(acc[i][2]), tanhf(acc[i][3]));
  {
    float* sWs2 = (float*)sW16;   // 512 f32 = 2 KB, reuse LDS
    sWs2[tid]       = Ws2[(size_t)r * 512 + tid];
    sWs2[tid + 256] = Ws2[(size_t)r * 512 + tid + 256];
  }
  __syncthreads();

  // ---- scores = tanh(...) @ Ws2[r] -> S ----
  if (tid < TN * 4) {
    const float* sWs2 = (const float*)sW16;
    const int i = tid >> 2;
    const int k = tid & 3;
    float a = 0.f;
#pragma unroll 8
    for (int q = 0; q < DD; ++q) a = fmaf(sA[i][q], sWs2[q * 4 + k], a);
    const int n = n0 + i;
    if (n < NN) S[((size_t)r * NN + n) * 4 + k] = a;
  }
}

// -------- softmax over relations + final mix (in place on out) --------
__global__ __launch_bounds__(256)
void k_combine(const float* __restrict__ S, float* __restrict__ out) {
  const long gw = (((long)blockIdx.x * 256) + threadIdx.x) >> 6;
  const int lane = threadIdx.x & 63;
  if (gw >= NN) return;
  const int n = (int)gw;
  float a[4][4];
#pragma unroll
  for (int r = 0; r < 4; ++r)
#pragma unroll
    for (int k = 0; k < 4; ++k)
      a[r][k] = S[((size_t)r * NN + n) * 4 + k];
#pragma unroll
  for (int k = 0; k < 4; ++k) {
    const float m = fmaxf(fmaxf(a[0][k], a[1][k]), fmaxf(a[2][k], a[3][k]));
    const float e0 = expf(a[0][k] - m);
    const float e1 = expf(a[1][k] - m);
    const float e2 = expf(a[2][k] - m);
    const float e3 = expf(a[3][k] - m);
    const float inv = 1.f / (e0 + e1 + e2 + e3);
    a[0][k] = e0 * inv; a[1][k] = e1 * inv; a[2][k] = e2 * inv; a[3][k] = e3 * inv;
  }
  float2 hv[4];
#pragma unroll
  for (int k = 0; k < 4; ++k)
    hv[k] = *(const float2*)(out + ((size_t)n * RR + k) * DD + lane * 2);
#pragma unroll
  for (int r = 0; r < 4; ++r) {
    float2 o;
    o.x = a[r][0] * hv[0].x + a[r][1] * hv[1].x + a[r][2] * hv[2].x + a[r][3] * hv[3].x;
    o.y = a[r][0] * hv[0].y + a[r][1] * hv[1].y + a[r][2] * hv[2].y + a[r][3] * hv[3].y;
    *(float2*)(out + ((size_t)n * RR + r) * DD + lane * 2) = o;
  }
}

extern "C" void kernel_launch(void* const* d_in, const int* in_sizes, int n_in,
                              void* d_out, int out_size, void* d_ws, size_t ws_size,
                              hipStream_t stream) {
  const float* nf    = (const float*)d_in[0];
  const int*   src   = (const int*)d_in[1];
  const int*   dst   = (const int*)d_in[2];
  const float* W1    = (const float*)d_in[3];
  const float* b1    = (const float*)d_in[4];
  const float* W2    = (const float*)d_in[5];
  const float* b2    = (const float*)d_in[6];
  const float* Ws1   = (const float*)d_in[7];
  const float* Ws2   = (const float*)d_in[8];
  const float* gamma = (const float*)d_in[9];
  const float* beta  = (const float*)d_in[10];
  float* out = (float*)d_out;

  // ws layout (~136 MB; ws proven >= 211 MB in round 5):
  //   S      : RR*NN*4 f32   (6.4 MB)
  //   off    : RR*(NN+1) int (1.6 MB)  written entirely by k_place
  //   cnt    : RR*NB int               bucket counts (memset)
  //   bOff   : RR*(NB+1) int           bucket bases
  //   gcur   : RR*NB int               bin cursors
  //   w16    : 6*8192 u32    (0.2 MB)  bf16-packed W1,W2,Ws1[0..3]
  //   sorted : RR*EE int     (25.6 MB) src grouped by dst
  //   big    : max(pairs RR*EE int2 = 51.2 MB, nf16 RR*NN*64 u32 = 102.4 MB)
  float* S      = (float*)d_ws;
  int*   off    = (int*)(S + (size_t)RR * NN * 4);
  int*   cnt    = off + (size_t)RR * (NN + 1);
  int*   bOff   = cnt + (size_t)RR * NB;
  int*   gcur   = bOff + (size_t)RR * (NB + 1);
  u32*   w16    = (u32*)(gcur + (size_t)RR * NB);
  int*   sorted = (int*)(w16 + (size_t)6 * 8192);
  int2*  pairs  = (int2*)(sorted + (size_t)RR * EE);
  u32*   nf16   = (u32*)pairs;   // alias: valid only after k_place

  hipMemsetAsync(cnt, 0, (size_t)RR * NB * sizeof(int), stream);
  k_wcvt<<<dim3(192), dim3(256), 0, stream>>>(W1, W2, Ws1, w16);
  {
    dim3 grid((EE + CHUNK - 1) / CHUNK, RR);
    k_cnt<<<grid, dim3(256), 0, stream>>>(dst, cnt);
  }
  k_bscan<<<dim3(1), dim3(512), 0, stream>>>(cnt, bOff, gcur);
  {
    dim3 grid((EE + CHUNK - 1) / CHUNK, RR);
    k_bin<<<grid, dim3(256), 0, stream>>>(src, dst, gcur, pairs);
  }
  k_place<<<dim3(NB, RR), dim3(256), 0, stream>>>(pairs, bOff, off, sorted);
  {
    dim3 grid((unsigned)(((long)NN * 64 + 255) / 256), RR);
    k_cvt<<<grid, dim3(256), 0, stream>>>(nf, nf16);
  }
  for (int r = 0; r < RR; ++r) {
    dim3 grid((NN + TN - 1) / TN);
    k_mlp<<<grid, dim3(BLK), 0, stream>>>(nf, nf16 + (size_t)r * NN * 64, w16,
                                          b1, b2, Ws2, gamma, beta, off, sorted,
                                          S, out, r);
  }
  {
    const long blocks = ((long)NN + 3) / 4;  // 1 wave/node
    k_combine<<<dim3((unsigned)blocks), dim3(256), 0, stream>>>(S, out);
  }
}

// Round 18
// 1119.611 us; speedup vs baseline: 1.9239x; 1.1671x over previous
//
#include <hip/hip_runtime.h>
#include <stdint.h>

#define NN 100000
#define RR 4
#define EE 1600000
#define DD 128
#define TN 32
#define BLK 256
#define NB 98     // ceil(NN/1024) 1024-node buckets
#define CHUNK 2048

typedef unsigned int u32;
typedef unsigned short u16;

__device__ __forceinline__ u16 f2bf(float f) {
  union { float f; u32 i; } c; c.f = f;
  const u32 lsb = (c.i >> 16) & 1u;
  c.i += 0x7fffu + lsb;  // round-to-nearest-even
  return (u16)(c.i >> 16);
}
__device__ __forceinline__ u32 pack2(float a, float b) {
  return (u32)f2bf(a) | ((u32)f2bf(b) << 16);
}
__device__ __forceinline__ float u2f(u32 u) {
  union { u32 i; float f; } c; c.i = u; return c.f;
}

// ---------- pass 1: per-chunk LDS bucket histogram -> global bucket counts ----------
__global__ __launch_bounds__(256)
void k_cnt(const int* __restrict__ dst, int* __restrict__ cnt) {
  const int r = blockIdx.y;
  const long base = (long)blockIdx.x * CHUNK;
  const int t = threadIdx.x;
  __shared__ int hist[NB];
  for (int i = t; i < NB; i += 256) hist[i] = 0;
  __syncthreads();
#pragma unroll
  for (int k = 0; k < 8; ++k) {
    const long e = base + k * 256 + t;
    if (e < EE) atomicAdd(&hist[dst[(size_t)r * EE + e] >> 10], 1);
  }
  __syncthreads();
  if (t < NB && hist[t]) atomicAdd(&cnt[r * NB + t], hist[t]);
}

// ---------- pass 2: scan 4x98 bucket counts -> bucket bases + bin cursors ----------
__global__ __launch_bounds__(512)
void k_bscan(const int* __restrict__ cnt, int* __restrict__ bOff, int* __restrict__ gcur) {
  __shared__ int tmp[512];
  const int t = threadIdx.x;
  const int r = t >> 7, b = t & 127;
  const int v = (b < NB) ? cnt[r * NB + b] : 0;
  tmp[t] = v;
  __syncthreads();
  for (int o = 1; o < 128; o <<= 1) {
    const int y = (b >= o) ? tmp[t - o] : 0;
    __syncthreads();
    tmp[t] += y;
    __syncthreads();
  }
  if (b < NB) {
    const int excl = tmp[t] - v;
    bOff[r * (NB + 1) + b] = excl;
    gcur[r * NB + b] = excl;
    if (b == NB - 1) bOff[r * (NB + 1) + NB] = tmp[t];
  }
}

// ---------- pass 3: coarse binning with LDS-staged dense writes ----------
__global__ __launch_bounds__(256)
void k_bin(const int* __restrict__ src, const int* __restrict__ dst,
           int* __restrict__ gcur, int2* __restrict__ pairs) {
  const int r = blockIdx.y;
  const long base = (long)blockIdx.x * CHUNK;
  const int t = threadIdx.x;
  __shared__ int hist[NB], lofs[NB], gbase[NB], hcur[NB];
  __shared__ int2 stage[CHUNK];  // 16 KB
  for (int i = t; i < NB; i += 256) hist[i] = 0;
  __syncthreads();
  int d[8], s[8];
#pragma unroll
  for (int k = 0; k < 8; ++k) {
    const long e = base + k * 256 + t;
    if (e < EE) {
      d[k] = dst[(size_t)r * EE + e];
      s[k] = src[(size_t)r * EE + e];
      atomicAdd(&hist[d[k] >> 10], 1);
    } else d[k] = -1;
  }
  __syncthreads();
  if (t == 0) {
    int run = 0;
    for (int b = 0; b < NB; ++b) { lofs[b] = run; run += hist[b]; }
  }
  __syncthreads();
  if (t < NB) {
    hcur[t] = 0;
    gbase[t] = hist[t] ? atomicAdd(&gcur[r * NB + t], hist[t]) : 0;
  }
  __syncthreads();
#pragma unroll
  for (int k = 0; k < 8; ++k) {
    if (d[k] >= 0) {
      const int b = d[k] >> 10;
      const int slot = lofs[b] + atomicAdd(&hcur[b], 1);
      stage[slot] = make_int2(d[k], s[k]);
    }
  }
  __syncthreads();
  const int total = (int)((EE - base < CHUNK) ? (EE - base) : CHUNK);
  for (int i = t; i < total; i += 256) {
    const int2 p = stage[i];
    const int b = p.x >> 10;
    pairs[(size_t)r * EE + gbase[b] + (i - lofs[b])] = p;
  }
}

// ---------- pass 4: in-bucket CSR build + placement, all LDS atomics ----------
__global__ __launch_bounds__(256)
void k_place(const int2* __restrict__ pairs, const int* __restrict__ bOff,
             int* __restrict__ off, int* __restrict__ sorted) {
  const int r = blockIdx.y;
  const int b = blockIdx.x;
  const int nlo = b << 10;
  const int span0 = bOff[r * (NB + 1) + b];
  const int span1 = bOff[r * (NB + 1) + b + 1];
  const int t = threadIdx.x;
  __shared__ __align__(16) int ncnt[1024];
  __shared__ int part[256];
  ((int4*)ncnt)[t] = make_int4(0, 0, 0, 0);
  __syncthreads();
  for (int i = span0 + t; i < span1; i += 256)
    atomicAdd(&ncnt[pairs[(size_t)r * EE + i].x - nlo], 1);
  __syncthreads();
  const int4 c = ((int4*)ncnt)[t];
  const int s = c.x + c.y + c.z + c.w;
  part[t] = s;
  __syncthreads();
  for (int o = 1; o < 256; o <<= 1) {
    const int y = (t >= o) ? part[t - o] : 0;
    __syncthreads();
    part[t] += y;
    __syncthreads();
  }
  const int base = part[t] - s;
  int ex[4];
  ex[0] = base;
  ex[1] = base + c.x;
  ex[2] = base + c.x + c.y;
  ex[3] = base + c.x + c.y + c.z;
  ((int4*)ncnt)[t] = make_int4(ex[0], ex[1], ex[2], ex[3]);
#pragma unroll
  for (int j = 0; j < 4; ++j) {
    const int n = nlo + t * 4 + j;
    if (n < NN) off[(size_t)r * (NN + 1) + n] = span0 + ex[j];
  }
  if (b == NB - 1 && t == 0) off[(size_t)r * (NN + 1) + NN] = span1;
  __syncthreads();
  for (int i = span0 + t; i < span1; i += 256) {
    const int2 p = pairs[(size_t)r * EE + i];
    const int pos = atomicAdd(&ncnt[p.x - nlo], 1);
    sorted[(size_t)r * EE + span0 + pos] = p.y;
  }
}

// ---------- convert ALL relations' features to packed bf16 rows ----------
__global__ __launch_bounds__(256)
void k_cvt(const float* __restrict__ nf, u32* __restrict__ nf16) {
  const int r = blockIdx.y;
  const long t = (long)blockIdx.x * 256 + threadIdx.x;
  if (t >= (long)NN * 64) return;
  const int n = (int)(t >> 6);
  const int l = (int)(t & 63);
  const float2 v = *(const float2*)(nf + ((size_t)n * RR + r) * DD + l * 2);
  nf16[(size_t)r * NN * 64 + t] = pack2(v.x, v.y);
}

// ---------- pre-convert weights to packed bf16 (row-major pairs) ----------
// w16 layout: [mat][8192] u32 pairs; mat 0=W1, 1=W2, 2..5=Ws1[r]
__global__ __launch_bounds__(256)
void k_wcvt(const float* __restrict__ W1, const float* __restrict__ W2,
            const float* __restrict__ Ws1, u32* __restrict__ w16) {
  const int i = blockIdx.x * 256 + threadIdx.x;
  if (i >= 6 * 8192) return;
  const int m = i >> 13;
  const int p = i & 8191;
  const float* srcm = (m == 0) ? W1 : (m == 1) ? W2 : Ws1 + (size_t)(m - 2) * DD * DD;
  const float2 v = *(const float2*)(srcm + (size_t)p * 2);
  w16[i] = pack2(v.x, v.y);
}

// ---- copy one 64-row half of a bf16-packed 128x128 weight into LDS (16 KB) ----
__device__ __forceinline__ void loadWh16(const u32* __restrict__ Wsrc, int half,
                                         u32* __restrict__ sW16, int tid) {
  const uint4* src = (const uint4*)(Wsrc + (size_t)half * 64 * 64);
  uint4* dstv = (uint4*)sW16;
#pragma unroll
  for (int k = 0; k < 4; ++k) dstv[tid + k * BLK] = src[tid + k * BLK];  // 1024 uint4
}

// ---- 4x4-blocked half-K gemm with bf16-packed weights (round-13 proven) ----
__device__ __forceinline__ void gemm4x4(const float (*__restrict__ in)[DD],
                                        const u32* __restrict__ sW16,
                                        int rg, int c2, int kbase, float acc[4][4]) {
  for (int k4 = 0; k4 < 64; k4 += 4) {
    const float4 a0 = *(const float4*)(&in[rg + 0][kbase + k4]);
    const float4 a1 = *(const float4*)(&in[rg + 1][kbase + k4]);
    const float4 a2 = *(const float4*)(&in[rg + 2][kbase + k4]);
    const float4 a3 = *(const float4*)(&in[rg + 3][kbase + k4]);
    const uint2 p0 = *(const uint2*)(&sW16[(k4 + 0) * 64 + c2]);
    const uint2 p1 = *(const uint2*)(&sW16[(k4 + 1) * 64 + c2]);
    const uint2 p2 = *(const uint2*)(&sW16[(k4 + 2) * 64 + c2]);
    const uint2 p3 = *(const uint2*)(&sW16[(k4 + 3) * 64 + c2]);
    const float4 w0 = make_float4(u2f(p0.x << 16), u2f(p0.x & 0xffff0000u),
                                  u2f(p0.y << 16), u2f(p0.y & 0xffff0000u));
    const float4 w1 = make_float4(u2f(p1.x << 16), u2f(p1.x & 0xffff0000u),
                                  u2f(p1.y << 16), u2f(p1.y & 0xffff0000u));
    const float4 w2 = make_float4(u2f(p2.x << 16), u2f(p2.x & 0xffff0000u),
                                  u2f(p2.y << 16), u2f(p2.y & 0xffff0000u));
    const float4 w3 = make_float4(u2f(p3.x << 16), u2f(p3.x & 0xffff0000u),
                                  u2f(p3.y << 16), u2f(p3.y & 0xffff0000u));
#define ROWF(i, ai)                                                                               \
    acc[i][0] = fmaf(ai.x, w0.x, fmaf(ai.y, w1.x, fmaf(ai.z, w2.x, fmaf(ai.w, w3.x, acc[i][0])))); \
    acc[i][1] = fmaf(ai.x, w0.y, fmaf(ai.y, w1.y, fmaf(ai.z, w2.y, fmaf(ai.w, w3.y, acc[i][1])))); \
    acc[i][2] = fmaf(ai.x, w0.z, fmaf(ai.y, w1.z, fmaf(ai.z, w2.z, fmaf(ai.w, w3.z, acc[i][2])))); \
    acc[i][3] = fmaf(ai.x, w0.w, fmaf(ai.y, w1.w, fmaf(ai.z, w2.w, fmaf(ai.w, w3.w, acc[i][3]))));
    ROWF(0, a0) ROWF(1, a1) ROWF(2, a2) ROWF(3, a3)
#undef ROWF
  }
}

// ------- fused: bf16 gather(CSR, 2-row interleaved) + MLP + LN + scores -------
// grid = (3125, RR); all 4 relations co-resident (102 MB nf16 fits L3).
__global__ __launch_bounds__(BLK, 5)
void k_mlp(const float* __restrict__ nf, const u32* __restrict__ nf16all,
           const u32* __restrict__ w16, const float* __restrict__ b1,
           const float* __restrict__ b2, const float* __restrict__ Ws2,
           const float* __restrict__ gamma, const float* __restrict__ beta,
           const int* __restrict__ off, const int* __restrict__ sortedSrc,
           float* __restrict__ S, float* __restrict__ out) {
  __shared__ float sA[TN][DD];                   // 16 KB
  __shared__ __align__(16) u32 sW16[64 * 64];    // 16 KB  (total 32 KB -> 5 blocks/CU)

  const int tid = threadIdx.x;
  const int r = blockIdx.y;
  const int n0 = blockIdx.x * TN;
  const int rg = (tid >> 5) * 4;   // 8 row groups of 4
  const int c4 = (tid & 31) * 4;   // 32 col groups of 4
  const int c2 = c4 >> 1;          // u32-pair column index

  const u32* Wg1 = w16;
  const u32* Wg2 = w16 + 8192;
  const u32* Wg3 = w16 + (size_t)(2 + r) * 8192;
  const u32* nf16 = nf16all + (size_t)r * NN * 64;

  // ---- stage rst = feat(f32) + bf16-gather(CSR) -> sA ----
  // 2-row interleave: 8+8 loads in flight to double memory-level parallelism.
  {
    const int wv = tid >> 6;
    const int lane = tid & 63;
    const int* ss = sortedSrc + (size_t)r * EE;
    const int* offr = off + (size_t)r * (NN + 1);
#pragma unroll
    for (int qp = 0; qp < 4; ++qp) {
      const int i0 = wv * 8 + qp * 2;
      const int i1 = i0 + 1;
      const int na = n0 + i0, nb = n0 + i1;   // always < NN (NN % TN == 0)
      float2 a0 = *(const float2*)(nf + ((size_t)na * RR + r) * DD + lane * 2);
      float2 a1 = *(const float2*)(nf + ((size_t)nb * RR + r) * DD + lane * 2);
      int e0 = offr[na], E0 = offr[na + 1];
      int e1 = offr[nb], E1 = offr[nb + 1];
      // joint phase: both rows issue 8 loads each (16 in flight)
      while (e0 + 8 <= E0 && e1 + 8 <= E1) {
        u32 v0[8], v1[8];
#pragma unroll
        for (int k = 0; k < 8; ++k) v0[k] = nf16[((size_t)ss[e0 + k] << 6) + lane];
#pragma unroll
        for (int k = 0; k < 8; ++k) v1[k] = nf16[((size_t)ss[e1 + k] << 6) + lane];
#pragma unroll
        for (int k = 0; k < 8; ++k) {
          a0.x += u2f(v0[k] << 16);
          a0.y += u2f(v0[k] & 0xffff0000u);
        }
#pragma unroll
        for (int k = 0; k < 8; ++k) {
          a1.x += u2f(v1[k] << 16);
          a1.y += u2f(v1[k] & 0xffff0000u);
        }
        e0 += 8; e1 += 8;
      }
      // drain row 0
      for (; e0 + 8 <= E0; e0 += 8) {
        u32 v[8];
#pragma unroll
        for (int k = 0; k < 8; ++k) v[k] = nf16[((size_t)ss[e0 + k] << 6) + lane];
#pragma unroll
        for (int k = 0; k < 8; ++k) {
          a0.x += u2f(v[k] << 16);
          a0.y += u2f(v[k] & 0xffff0000u);
        }
      }
      for (; e0 < E0; ++e0) {
        const u32 v = nf16[((size_t)ss[e0] << 6) + lane];
        a0.x += u2f(v << 16);
        a0.y += u2f(v & 0xffff0000u);
      }
      // drain row 1
      for (; e1 + 8 <= E1; e1 += 8) {
        u32 v[8];
#pragma unroll
        for (int k = 0; k < 8; ++k) v[k] = nf16[((size_t)ss[e1 + k] << 6) + lane];
#pragma unroll
        for (int k = 0; k < 8; ++k) {
          a1.x += u2f(v[k] << 16);
          a1.y += u2f(v[k] & 0xffff0000u);
        }
      }
      for (; e1 < E1; ++e1) {
        const u32 v = nf16[((size_t)ss[e1] << 6) + lane];
        a1.x += u2f(v << 16);
        a1.y += u2f(v & 0xffff0000u);
      }
      *(float2*)(&sA[i0][lane * 2]) = a0;
      *(float2*)(&sA[i1][lane * 2]) = a1;
    }
  }
  loadWh16(Wg1, 0, sW16, tid);
  __syncthreads();

  float acc[4][4];
#pragma unroll
  for (int i = 0; i < 4; ++i)
#pragma unroll
    for (int jj = 0; jj < 4; ++jj) acc[i][jj] = 0.f;

  // ---- GEMM1 ----
  gemm4x4(sA, sW16, rg, c2, 0, acc);
  __syncthreads();
  loadWh16(Wg1, 1, sW16, tid);
  __syncthreads();
  gemm4x4(sA, sW16, rg, c2, 64, acc);
  __syncthreads();
  {
    const float4 bb = *(const float4*)(&b1[c4]);
#pragma unroll
    for (int i = 0; i < 4; ++i)
      *(float4*)(&sA[rg + i][c4]) = make_float4(
          fmaxf(acc[i][0] + bb.x, 0.f), fmaxf(acc[i][1] + bb.y, 0.f),
          fmaxf(acc[i][2] + bb.z, 0.f), fmaxf(acc[i][3] + bb.w, 0.f));
  }
  loadWh16(Wg2, 0, sW16, tid);
  __syncthreads();

  // ---- GEMM2 ----
#pragma unroll
  for (int i = 0; i < 4; ++i)
#pragma unroll
    for (int jj = 0; jj < 4; ++jj) acc[i][jj] = 0.f;
  gemm4x4(sA, sW16, rg, c2, 0, acc);
  __syncthreads();
  loadWh16(Wg2, 1, sW16, tid);
  __syncthreads();
  gemm4x4(sA, sW16, rg, c2, 64, acc);
  __syncthreads();
  {
    const float4 bb = *(const float4*)(&b2[c4]);
#pragma unroll
    for (int i = 0; i < 4; ++i)
      *(float4*)(&sA[rg + i][c4]) = make_float4(
          fmaxf(acc[i][0] + bb.x, 0.f), fmaxf(acc[i][1] + bb.y, 0.f),
          fmaxf(acc[i][2] + bb.z, 0.f), fmaxf(acc[i][3] + bb.w, 0.f));
  }
  loadWh16(Wg3, 0, sW16, tid);
  __syncthreads();

  // ---- LayerNorm (8 threads/row, stats in registers via shfl) ----
  {
    const int i = tid >> 3;          // 0..31
    const int c0 = (tid & 7) * 16;
    float s = 0.f, s2 = 0.f;
    float hv[16];
#pragma unroll
    for (int c = 0; c < 16; ++c) {
      const float v = sA[i][c0 + c];
      hv[c] = v;
      s += v; s2 += v * v;
    }
#pragma unroll
    for (int off2 = 1; off2 < 8; off2 <<= 1) {
      s  += __shfl_xor(s, off2);
      s2 += __shfl_xor(s2, off2);
    }
    const float mu = s * (1.f / 128.f);
    const float var = fmaxf(s2 * (1.f / 128.f) - mu * mu, 0.f);
    const float rs = rsqrtf(var + 1e-5f);
    const int n = n0 + i;
#pragma unroll
    for (int c = 0; c < 16; ++c) {
      hv[c] = (hv[c] - mu) * rs * gamma[c0 + c] + beta[c0 + c];
      sA[i][c0 + c] = hv[c];   // own slice only: no cross-thread hazard
    }
    if (n < NN) {
      float4* op = (float4*)(out + ((size_t)n * RR + r) * DD + c0);
#pragma unroll
      for (int q = 0; q < 4; ++q)
        op[q] = make_float4(hv[q * 4], hv[q * 4 + 1], hv[q * 4 + 2], hv[q * 4 + 3]);
    }
  }
  __syncthreads();

  // ---- GEMM3: tanh(h @ Ws1[r]) ----
#pragma unroll
  for (int i = 0; i < 4; ++i)
#pragma unroll
    for (int jj = 0; jj < 4; ++jj) acc[i][jj] = 0.f;
  gemm4x4(sA, sW16, rg, c2, 0, acc);
  __syncthreads();
  loadWh16(Wg3, 1, sW16, tid);
  __syncthreads();
  gemm4x4(sA, sW16, rg, c2, 64, acc);
  __syncthreads();
#pragma unroll
  for (int i = 0; i < 4; ++i)
    *(float4*)(&sA[rg + i][c4]) = make_float4(
        tanhf(acc[i][0]), tanhf(acc[i][1]), tanhf(acc[i][2]), tanhf(acc[i][3]));
  {
    float* sWs2 = (float*)sW16;   // 512 f32 = 2 KB, reuse LDS
    sWs2[tid]       = Ws2[(size_t)r * 512 + tid];
    sWs2[tid + 256] = Ws2[(size_t)r * 512 + tid + 256];
  }
  __syncthreads();

  // ---- scores = tanh(...) @ Ws2[r] -> S ----
  if (tid < TN * 4) {
    const float* sWs2 = (const float*)sW16;
    const int i = tid >> 2;
    const int k = tid & 3;
    float a = 0.f;
#pragma unroll 8
    for (int q = 0; q < DD; ++q) a = fmaf(sA[i][q], sWs2[q * 4 + k], a);
    const int n = n0 + i;
    if (n < NN) S[((size_t)r * NN + n) * 4 + k] = a;
  }
}

// -------- softmax over relations + final mix (in place on out) --------
__global__ __launch_bounds__(256)
void k_combine(const float* __restrict__ S, float* __restrict__ out) {
  const long gw = (((long)blockIdx.x * 256) + threadIdx.x) >> 6;
  const int lane = threadIdx.x & 63;
  if (gw >= NN) return;
  const int n = (int)gw;
  float a[4][4];
#pragma unroll
  for (int r = 0; r < 4; ++r)
#pragma unroll
    for (int k = 0; k < 4; ++k)
      a[r][k] = S[((size_t)r * NN + n) * 4 + k];
#pragma unroll
  for (int k = 0; k < 4; ++k) {
    const float m = fmaxf(fmaxf(a[0][k], a[1][k]), fmaxf(a[2][k], a[3][k]));
    const float e0 = expf(a[0][k] - m);
    const float e1 = expf(a[1][k] - m);
    const float e2 = expf(a[2][k] - m);
    const float e3 = expf(a[3][k] - m);
    const float inv = 1.f / (e0 + e1 + e2 + e3);
    a[0][k] = e0 * inv; a[1][k] = e1 * inv; a[2][k] = e2 * inv; a[3][k] = e3 * inv;
  }
  float2 hv[4];
#pragma unroll
  for (int k = 0; k < 4; ++k)
    hv[k] = *(const float2*)(out + ((size_t)n * RR + k) * DD + lane * 2);
#pragma unroll
  for (int r = 0; r < 4; ++r) {
    float2 o;
    o.x = a[r][0] * hv[0].x + a[r][1] * hv[1].x + a[r][2] * hv[2].x + a[r][3] * hv[3].x;
    o.y = a[r][0] * hv[0].y + a[r][1] * hv[1].y + a[r][2] * hv[2].y + a[r][3] * hv[3].y;
    *(float2*)(out + ((size_t)n * RR + r) * DD + lane * 2) = o;
  }
}

extern "C" void kernel_launch(void* const* d_in, const int* in_sizes, int n_in,
                              void* d_out, int out_size, void* d_ws, size_t ws_size,
                              hipStream_t stream) {
  const float* nf    = (const float*)d_in[0];
  const int*   src   = (const int*)d_in[1];
  const int*   dst   = (const int*)d_in[2];
  const float* W1    = (const float*)d_in[3];
  const float* b1    = (const float*)d_in[4];
  const float* W2    = (const float*)d_in[5];
  const float* b2    = (const float*)d_in[6];
  const float* Ws1   = (const float*)d_in[7];
  const float* Ws2   = (const float*)d_in[8];
  const float* gamma = (const float*)d_in[9];
  const float* beta  = (const float*)d_in[10];
  float* out = (float*)d_out;

  // ws layout (~136 MB; ws proven >= 211 MB in round 5):
  float* S      = (float*)d_ws;
  int*   off    = (int*)(S + (size_t)RR * NN * 4);
  int*   cnt    = off + (size_t)RR * (NN + 1);
  int*   bOff   = cnt + (size_t)RR * NB;
  int*   gcur   = bOff + (size_t)RR * (NB + 1);
  u32*   w16    = (u32*)(gcur + (size_t)RR * NB);
  int*   sorted = (int*)(w16 + (size_t)6 * 8192);
  int2*  pairs  = (int2*)(sorted + (size_t)RR * EE);
  u32*   nf16   = (u32*)pairs;   // alias: valid only after k_place

  hipMemsetAsync(cnt, 0, (size_t)RR * NB * sizeof(int), stream);
  k_wcvt<<<dim3(192), dim3(256), 0, stream>>>(W1, W2, Ws1, w16);
  {
    dim3 grid((EE + CHUNK - 1) / CHUNK, RR);
    k_cnt<<<grid, dim3(256), 0, stream>>>(dst, cnt);
  }
  k_bscan<<<dim3(1), dim3(512), 0, stream>>>(cnt, bOff, gcur);
  {
    dim3 grid((EE + CHUNK - 1) / CHUNK, RR);
    k_bin<<<grid, dim3(256), 0, stream>>>(src, dst, gcur, pairs);
  }
  k_place<<<dim3(NB, RR), dim3(256), 0, stream>>>(pairs, bOff, off, sorted);
  {
    dim3 grid((unsigned)(((long)NN * 64 + 255) / 256), RR);
    k_cvt<<<grid, dim3(256), 0, stream>>>(nf, nf16);
  }
  {
    dim3 grid((NN + TN - 1) / TN, RR);   // single merged launch, all relations
    k_mlp<<<grid, dim3(BLK), 0, stream>>>(nf, nf16, w16, b1, b2, Ws2,
                                          gamma, beta, off, sorted, S, out);
  }
  {
    const long blocks = ((long)NN + 3) / 4;  // 1 wave/node
    k_combine<<<dim3((unsigned)blocks), dim3(256), 0, stream>>>(S, out);
  }
}